// Round 3
// baseline (863.759 us; speedup 1.0000x reference)
//
#include <hip/hip_runtime.h>

#define NPTS 262144
#define KVOL 27
#define NPAIRS 65536
#define TP (KVOL*NPAIRS)     // 1769472 total pairs
#define CH 64
#define BROWS 256            // output rows per bucket
#define NB (NPTS/BROWS)      // 1024 buckets
#define NSEG (NB*32)         // segments, k padded to stride 32
#define LPAD 68              // LDS accumulator row stride (floats), breaks bank alignment

typedef __attribute__((ext_vector_type(8))) short bf16x8;
typedef __attribute__((ext_vector_type(4))) float f32x4;

__device__ inline unsigned short f2bf(float x){
  unsigned int u = __float_as_uint(x);
  u += 0x7FFFu + ((u >> 16) & 1u);   // RNE
  return (unsigned short)(u >> 16);
}

__device__ inline bf16x8 pack8(float4 a, float4 b){
  bf16x8 r;
  r[0]=(short)f2bf(a.x); r[1]=(short)f2bf(a.y); r[2]=(short)f2bf(a.z); r[3]=(short)f2bf(a.w);
  r[4]=(short)f2bf(b.x); r[5]=(short)f2bf(b.y); r[6]=(short)f2bf(b.z); r[7]=(short)f2bf(b.w);
  return r;
}

// ---- feat fp32 -> bf16 ----
__global__ void k_conv_feat(const float* __restrict__ f, unsigned short* __restrict__ o){
  int i = blockIdx.x * blockDim.x + threadIdx.x;   // NPTS*CH/4
  float4 v = ((const float4*)f)[i];
  ushort4 r;
  r.x = f2bf(v.x); r.y = f2bf(v.y); r.z = f2bf(v.z); r.w = f2bf(v.w);
  ((ushort4*)o)[i] = r;
}

// ---- weight fp32 [K][Cin][Cout] -> bf16 packed [k][kb][col][j] ----
__global__ void k_pack_w(const float* __restrict__ w, unsigned short* __restrict__ o){
  int i = blockIdx.x * blockDim.x + threadIdx.x;
  if (i >= KVOL*CH*CH) return;
  int j = i & 7, col = (i >> 3) & 63, kb = (i >> 9) & 7, k = i >> 12;
  o[i] = f2bf(w[(k*CH + kb*8 + j)*CH + col]);
}

// ---- pass A: histogram pairs into (bucket,k) segments ----
__global__ void k_count(const int2* __restrict__ km, int* __restrict__ cnt){
  int i = blockIdx.x*256 + threadIdx.x;   // TP threads
  int2 io = km[i];
  int k = i >> 16;                        // NPAIRS = 65536 per k
  atomicAdd(&cnt[((io.y >> 8) << 5) | k], 1);
}

// ---- pass B: exclusive prefix scan of 32768 counters (single block) ----
__global__ void k_scan(const int* __restrict__ cnt, int* __restrict__ off, int* __restrict__ cursor){
  int t = threadIdx.x;                    // 1024 threads, 32 counters each
  int base = t*32;
  int loc[32]; int sum = 0;
  #pragma unroll
  for (int i = 0; i < 32; i++){ loc[i] = sum; sum += cnt[base+i]; }
  int l = t & 63;
  int v = sum;
  #pragma unroll
  for (int d = 1; d < 64; d <<= 1){ int u = __shfl_up(v, d, 64); if (l >= d) v += u; }
  __shared__ int wt[16], wbase[16];
  if (l == 63) wt[t>>6] = v;
  __syncthreads();
  if (t == 0){ int a = 0; for (int w = 0; w < 16; w++){ wbase[w] = a; a += wt[w]; } }
  __syncthreads();
  int tb = wbase[t>>6] + v - sum;         // exclusive base for this thread
  #pragma unroll
  for (int i = 0; i < 32; i++){ int x = tb + loc[i]; off[base+i] = x; cursor[base+i] = x; }
  if (t == 1023) off[NSEG] = tb + sum;
}

// ---- pass C: scatter packed records (in:18b | outlo:8b) ----
__global__ void k_scatter(const int2* __restrict__ km, int* __restrict__ cursor,
                          int* __restrict__ records){
  int i = blockIdx.x*256 + threadIdx.x;
  int2 io = km[i];
  int k = i >> 16;
  int pos = atomicAdd(&cursor[((io.y >> 8) << 5) | k], 1);
  records[pos] = io.x | ((io.y & 255) << 18);
}

// ---- pass D: bucketed conv. Block=bucket, waves own k-ranges, LDS accumulator ----
template<bool BF16G>
__global__ __launch_bounds__(256, 2) void k_conv3(
    const unsigned short* __restrict__ featb, const float* __restrict__ featf,
    const unsigned short* __restrict__ wpack, const int* __restrict__ records,
    const int* __restrict__ off, float* __restrict__ out, float* __restrict__ stats)
{
  extern __shared__ float sm[];
  float* acc_s = sm;                 // BROWS*LPAD floats
  float* red   = sm + BROWS*LPAD;    // 256 floats
  int b = blockIdx.x;
  int tid = threadIdx.x;
  int wv = tid>>6, l = tid&63, lg = l>>4, li = l&15;

  for (int i = tid; i < BROWS*LPAD/4; i += 256) ((float4*)acc_s)[i] = make_float4(0,0,0,0);
  __syncthreads();

  const bf16x8* wp = (const bf16x8*)wpack;
  const bf16x8* fb = (const bf16x8*)featb;
  const float4* ff = (const float4*)featf;

  int kbeg = (wv*KVOL) >> 2, kend = ((wv+1)*KVOL) >> 2;
  for (int k = kbeg; k < kend; k++){
    int s = (b << 5) | k;
    int beg = off[s], cnt = off[s+1] - beg;
    if (cnt == 0) continue;
    // B fragments for offset k (loaded once per wave per k, L2-hot)
    bf16x8 B[4][2];
    #pragma unroll
    for (int t = 0; t < 4; t++)
      #pragma unroll
      for (int kk = 0; kk < 2; kk++)
        B[t][kk] = wp[(k*8 + kk*4 + lg)*64 + t*16 + li];

    int nch = (cnt + 63) >> 6;
    for (int ch = 0; ch < nch; ch++){
      int slot = ch*64 + l;
      int rec = (slot < cnt) ? records[beg + slot] : 0;
      int rin = rec & 0x3FFFF, rout = rec >> 18;
      int rem = cnt - ch*64;
      int ng = (rem >= 64) ? 4 : ((rem + 15) >> 4);

      // batch-gather A fragments for up to 4 groups (8 outstanding loads/lane)
      bf16x8 A0[4], A1[4];
      #pragma unroll
      for (int g = 0; g < 4; g++){
        if (g < ng){
          int inl = __shfl(rin, g*16 + li, 64);
          if (BF16G){
            A0[g] = fb[inl*8 + lg];
            A1[g] = fb[inl*8 + 4 + lg];
          } else {
            float4 u0 = ff[inl*16 + lg*2],     u1 = ff[inl*16 + lg*2 + 1];
            float4 u2 = ff[inl*16 + 8 + lg*2], u3 = ff[inl*16 + 8 + lg*2 + 1];
            A0[g] = pack8(u0, u1);
            A1[g] = pack8(u2, u3);
          }
        }
      }
      #pragma unroll
      for (int g = 0; g < 4; g++){
        if (g < ng){
          f32x4 acc[4];
          #pragma unroll
          for (int t = 0; t < 4; t++){
            acc[t] = (f32x4)(0.0f);
            acc[t] = __builtin_amdgcn_mfma_f32_16x16x32_bf16(A0[g], B[t][0], acc[t], 0, 0, 0);
            acc[t] = __builtin_amdgcn_mfma_f32_16x16x32_bf16(A1[g], B[t][1], acc[t], 0, 0, 0);
          }
          int orow[4];
          #pragma unroll
          for (int r = 0; r < 4; r++) orow[r] = __shfl(rout, g*16 + lg*4 + r, 64);
          #pragma unroll
          for (int r = 0; r < 4; r++){
            if (ch*64 + g*16 + lg*4 + r < cnt){
              float* basep = acc_s + orow[r]*LPAD;
              #pragma unroll
              for (int t = 0; t < 4; t++)
                atomicAdd(basep + t*16 + li, acc[t][r]);
            }
          }
        }
      }
    }
  }
  __syncthreads();

  // fused per-channel stats for BN
  int c = tid & 63, rg = tid >> 6;
  float s1 = 0.f, s2 = 0.f;
  for (int row = rg; row < BROWS; row += 4){
    float v = acc_s[row*LPAD + c];
    s1 += v; s2 += v*v;
  }
  red[tid] = s1; __syncthreads();
  if (tid < 64) s1 = red[tid] + red[tid+64] + red[tid+128] + red[tid+192];
  __syncthreads();
  red[tid] = s2; __syncthreads();
  if (tid < 64){
    s2 = red[tid] + red[tid+64] + red[tid+128] + red[tid+192];
    atomicAdd(&stats[tid], s1);
    atomicAdd(&stats[64 + tid], s2);
  }

  // coalesced non-atomic bucket flush (un-pad LPAD -> CH)
  float4* ob = (float4*)(out + (size_t)b*BROWS*CH);
  for (int i = tid; i < BROWS*CH/4; i += 256){
    int row = i >> 4, c4 = i & 15;
    ob[i] = ((const float4*)(acc_s + row*LPAD))[c4];
  }
}

// ---- BN (batch stats, biased var) + ReLU, in place ----
__global__ void k_bn(float* __restrict__ out, const float* __restrict__ stats,
                     const float* __restrict__ g, const float* __restrict__ b){
  int i = blockIdx.x * blockDim.x + threadIdx.x;  // NPTS*CH/4
  float4 v = ((const float4*)out)[i];
  int c0 = (i * 4) & 63;
  float vals[4] = {v.x, v.y, v.z, v.w};
  float res[4];
  #pragma unroll
  for (int q = 0; q < 4; q++){
    int c = c0 + q;
    float mean = stats[c] * (1.0f/NPTS);
    float var  = stats[64+c] * (1.0f/NPTS) - mean*mean;
    float inv  = rsqrtf(var + 1e-5f);
    float y = (vals[q] - mean) * inv * g[c] + b[c];
    res[q] = fmaxf(y, 0.0f);
  }
  float4 r; r.x=res[0]; r.y=res[1]; r.z=res[2]; r.w=res[3];
  ((float4*)out)[i] = r;
}

extern "C" void kernel_launch(void* const* d_in, const int* in_sizes, int n_in,
                              void* d_out, int out_size, void* d_ws, size_t ws_size,
                              hipStream_t stream) {
  const float* feat   = (const float*)d_in[0];
  const int*   kmap   = (const int*)d_in[3];
  const float* weight = (const float*)d_in[4];
  const float* bnw    = (const float*)d_in[5];
  const float* bnb    = (const float*)d_in[6];
  float* out = (float*)d_out;

  char* ws = (char*)d_ws;
  size_t cur = 0;
  auto take = [&](size_t bytes){
    cur = (cur + 255) & ~(size_t)255;
    size_t p = cur; cur += bytes; return p;
  };
  float* stats          = (float*)(ws + take(2*CH*sizeof(float)));
  int* cnt              = (int*)(ws + take((size_t)NSEG*4));
  int* off              = (int*)(ws + take((size_t)(NSEG+1)*4));
  int* cursor           = (int*)(ws + take((size_t)NSEG*4));
  unsigned short* wpack = (unsigned short*)(ws + take((size_t)KVOL*CH*CH*2));
  int* records          = (int*)(ws + take((size_t)TP*4));
  size_t featb_off      = take((size_t)NPTS*CH*2);
  bool useBf16 = (ws_size >= cur);
  unsigned short* featb = (unsigned short*)(ws + featb_off);

  hipMemsetAsync(cnt, 0, (size_t)NSEG*4, stream);
  hipMemsetAsync(stats, 0, 2*CH*sizeof(float), stream);

  k_pack_w<<<(KVOL*CH*CH + 255)/256, 256, 0, stream>>>(weight, wpack);
  if (useBf16)
    k_conv_feat<<<NPTS*CH/4/256, 256, 0, stream>>>(feat, featb);

  const int2* km = (const int2*)kmap;
  k_count<<<TP/256, 256, 0, stream>>>(km, cnt);
  k_scan<<<1, 1024, 0, stream>>>(cnt, off, cursor);
  k_scatter<<<TP/256, 256, 0, stream>>>(km, cursor, records);

  size_t smem = (size_t)(BROWS*LPAD + 256) * sizeof(float);
  if (useBf16)
    k_conv3<true><<<NB, 256, smem, stream>>>(featb, feat, wpack, records, off, out, stats);
  else
    k_conv3<false><<<NB, 256, smem, stream>>>(featb, feat, wpack, records, off, out, stats);

  k_bn<<<NPTS*CH/4/256, 256, 0, stream>>>(out, stats, bnw, bnb);
}

// Round 4
// 507.414 us; speedup vs baseline: 1.7023x; 1.7023x over previous
//
#include <hip/hip_runtime.h>

#define NPTS 262144
#define KVOL 27
#define NPAIRS 65536
#define TP (KVOL*NPAIRS)     // 1769472 pairs
#define CH 64
#define NT16 (NPTS/16)       // 16384 16-row output tiles
#define NSEG (NT16*32)       // 524288 segments (k padded to 32)
#define NBLK 1024            // conv blocks (4 waves = 4 buckets of 64 rows)

typedef __attribute__((ext_vector_type(8))) short bf16x8;
typedef __attribute__((ext_vector_type(4))) float f32x4;

__device__ inline unsigned short f2bf(float x){
  unsigned int u = __float_as_uint(x);
  u += 0x7FFFu + ((u >> 16) & 1u);   // RNE
  return (unsigned short)(u >> 16);
}

__device__ inline bf16x8 pack8(float4 a, float4 b){
  bf16x8 r;
  r[0]=(short)f2bf(a.x); r[1]=(short)f2bf(a.y); r[2]=(short)f2bf(a.z); r[3]=(short)f2bf(a.w);
  r[4]=(short)f2bf(b.x); r[5]=(short)f2bf(b.y); r[6]=(short)f2bf(b.z); r[7]=(short)f2bf(b.w);
  return r;
}

// ---- feat fp32 -> bf16 ----
__global__ void k_conv_feat(const float* __restrict__ f, unsigned short* __restrict__ o){
  int i = blockIdx.x * blockDim.x + threadIdx.x;   // NPTS*CH/4
  float4 v = ((const float4*)f)[i];
  ushort4 r;
  r.x = f2bf(v.x); r.y = f2bf(v.y); r.z = f2bf(v.z); r.w = f2bf(v.w);
  ((ushort4*)o)[i] = r;
}

// ---- weight fp32 [K][Cin][Cout] -> bf16 packed [k][kb][col][j] ----
__global__ void k_pack_w(const float* __restrict__ w, unsigned short* __restrict__ o){
  int i = blockIdx.x * blockDim.x + threadIdx.x;
  if (i >= KVOL*CH*CH) return;
  int j = i & 7, col = (i >> 3) & 63, kb = (i >> 9) & 7, k = i >> 12;
  o[i] = f2bf(w[(k*CH + kb*8 + j)*CH + col]);
}

// ---- histogram pairs into (tile16,k) segments ----
__global__ void k_count(const int2* __restrict__ km, int* __restrict__ cnt){
  int i = blockIdx.x*256 + threadIdx.x;   // TP
  int2 io = km[i];
  int k = i >> 16;
  atomicAdd(&cnt[((io.y >> 4) << 5) | k], 1);
}

// ---- hierarchical exclusive scan over NSEG counters ----
__global__ void k_scan1(const int* __restrict__ cnt, int* __restrict__ loc, int* __restrict__ btot){
  int blk = blockIdx.x, t = threadIdx.x;        // 256 blocks x 256 thr, 8 segs/thr
  int base = blk*2048 + t*8;
  int c[8]; int s = 0;
  #pragma unroll
  for (int i = 0; i < 8; i++){ c[i] = s; s += cnt[base+i]; }
  int l = t & 63;
  int v = s;
  #pragma unroll
  for (int d = 1; d < 64; d <<= 1){ int u = __shfl_up(v, d, 64); if (l >= d) v += u; }
  __shared__ int wt[4], wb[4];
  if (l == 63) wt[t>>6] = v;
  __syncthreads();
  if (t == 0){ int a = 0; for (int w = 0; w < 4; w++){ wb[w] = a; a += wt[w]; } }
  __syncthreads();
  int tb = wb[t>>6] + v - s;
  #pragma unroll
  for (int i = 0; i < 8; i++) loc[base+i] = tb + c[i];
  if (t == 255) btot[blk] = tb + s;
}

__global__ void k_scan2(const int* __restrict__ btot, int* __restrict__ bbase){
  __shared__ int sm_[256];
  int t = threadIdx.x;
  int mine = btot[t];
  sm_[t] = mine;
  __syncthreads();
  for (int d = 1; d < 256; d <<= 1){
    int v = (t >= d) ? sm_[t-d] : 0;
    __syncthreads();
    sm_[t] += v;
    __syncthreads();
  }
  bbase[t] = sm_[t] - mine;   // exclusive
}

__global__ void k_init(int* __restrict__ loc, int* __restrict__ cursor, const int* __restrict__ bbase){
  int i = blockIdx.x*256 + threadIdx.x;   // NSEG
  int a = loc[i] + bbase[i >> 11];
  loc[i] = a; cursor[i] = a;
}

// ---- scatter packed records (in:18b | slot:4b) ----
__global__ void k_scatter(const int2* __restrict__ km, int* __restrict__ cursor,
                          int* __restrict__ records){
  int i = blockIdx.x*256 + threadIdx.x;
  int2 io = km[i];
  int k = i >> 16;
  int pos = atomicAdd(&cursor[((io.y >> 4) << 5) | k], 1);
  records[pos] = io.x | ((io.y & 15) << 18);
}

// ---- conv: wave owns 64 output rows; acc in registers; zero atomics/LDS in hot loop ----
template<bool BF16G>
__global__ __launch_bounds__(256, 2) void k_conv4(
    const unsigned short* __restrict__ featb, const float* __restrict__ featf,
    const unsigned short* __restrict__ wpack, const int* __restrict__ records,
    const int* __restrict__ loc, const int* __restrict__ cnt,
    float* __restrict__ out, float* __restrict__ partials)
{
  int tid = threadIdx.x;
  int wv = tid>>6, l = tid&63, lg = l>>4, li = l&15;
  int b4 = blockIdx.x*4 + wv;     // 64-row bucket

  const bf16x8* wp = (const bf16x8*)wpack;
  const bf16x8* fb = (const bf16x8*)featb;
  const float4* ff = (const float4*)featf;

  f32x4 acc[4][4];
  #pragma unroll
  for (int rt = 0; rt < 4; rt++)
    #pragma unroll
    for (int ct = 0; ct < 4; ct++) acc[rt][ct] = (f32x4)(0.0f);

  for (int k = 0; k < KVOL; k++){
    bf16x8 B[4][2];
    #pragma unroll
    for (int ct = 0; ct < 4; ct++)
      #pragma unroll
      for (int h = 0; h < 2; h++)
        B[ct][h] = wp[(k*8 + h*4 + lg)*64 + ct*16 + li];

    #pragma unroll
    for (int rt = 0; rt < 4; rt++){
      int seg = (((b4 << 2) | rt) << 5) | k;
      int beg = loc[seg], tot = cnt[seg];
      for (int c0 = 0; c0 < tot; c0 += 64){
        int cc = min(64, tot - c0);
        int rec = (l < cc) ? records[beg + c0 + l] : 0;
        // rank among lower active lanes with same slot (slot bits 18..21)
        int rank = 0;
        for (int j = 0; j < cc; j++){
          int sj = __builtin_amdgcn_readlane(rec, j);
          if (j < l && ((((unsigned)(sj ^ rec)) >> 18) & 15u) == 0u) rank++;
        }
        int rec2 = rec | (rank << 22);
        for (int r = 0; ; r++){
          int myin = -1;
          for (int j = 0; j < cc; j++){
            int v = __builtin_amdgcn_readlane(rec2, j);
            if ((v >> 22) == r && ((v >> 18) & 15) == li) myin = v & 0x3FFFF;
          }
          bf16x8 A0 = (bf16x8)(short)0, A1 = (bf16x8)(short)0;
          if (myin >= 0){
            if (BF16G){
              A0 = fb[myin*8 + lg];
              A1 = fb[myin*8 + 4 + lg];
            } else {
              float4 u0 = ff[myin*16 + lg*2],     u1 = ff[myin*16 + lg*2 + 1];
              float4 u2 = ff[myin*16 + 8 + lg*2], u3 = ff[myin*16 + 8 + lg*2 + 1];
              A0 = pack8(u0, u1);
              A1 = pack8(u2, u3);
            }
          }
          #pragma unroll
          for (int ct = 0; ct < 4; ct++){
            acc[rt][ct] = __builtin_amdgcn_mfma_f32_16x16x32_bf16(A0, B[ct][0], acc[rt][ct], 0, 0, 0);
            acc[rt][ct] = __builtin_amdgcn_mfma_f32_16x16x32_bf16(A1, B[ct][1], acc[rt][ct], 0, 0, 0);
          }
          if (__ballot((l < cc) && (rank > r)) == 0ull) break;
        }
      }
    }
  }

  // flush 64x64 from registers (coalesced within 64B rows)
  #pragma unroll
  for (int rt = 0; rt < 4; rt++)
    #pragma unroll
    for (int r = 0; r < 4; r++){
      int row = b4*64 + rt*16 + lg*4 + r;
      #pragma unroll
      for (int ct = 0; ct < 4; ct++)
        out[row*CH + ct*16 + li] = acc[rt][ct][r];
    }

  // BN stats: per-lane channel partials -> cross-lg shfl reduce -> block partials
  float s1[4], s2[4];
  #pragma unroll
  for (int ct = 0; ct < 4; ct++){
    float a1 = 0.f, a2 = 0.f;
    #pragma unroll
    for (int rt = 0; rt < 4; rt++)
      #pragma unroll
      for (int r = 0; r < 4; r++){
        float v = acc[rt][ct][r];
        a1 += v; a2 += v*v;
      }
    a1 += __shfl_xor(a1, 16, 64); a1 += __shfl_xor(a1, 32, 64);
    a2 += __shfl_xor(a2, 16, 64); a2 += __shfl_xor(a2, 32, 64);
    s1[ct] = a1; s2[ct] = a2;
  }
  __shared__ float sred[4][2][64];
  if (l < 16){
    #pragma unroll
    for (int ct = 0; ct < 4; ct++){
      sred[wv][0][ct*16 + li] = s1[ct];
      sred[wv][1][ct*16 + li] = s2[ct];
    }
  }
  __syncthreads();
  if (tid < 128){
    int h = tid >> 6, c = tid & 63;
    float p = sred[0][h][c] + sred[1][h][c] + sred[2][h][c] + sred[3][h][c];
    partials[blockIdx.x*128 + tid] = p;
  }
}

// ---- final stats reduce ----
__global__ void k_statred(const float* __restrict__ partials, float* __restrict__ stats){
  int t = threadIdx.x;   // 128
  float s = 0.f;
  for (int b = 0; b < NBLK; b++) s += partials[b*128 + t];
  stats[t] = s;
}

// ---- BN (batch stats, biased var) + ReLU, in place ----
__global__ void k_bn(float* __restrict__ out, const float* __restrict__ stats,
                     const float* __restrict__ g, const float* __restrict__ b){
  int i = blockIdx.x * blockDim.x + threadIdx.x;  // NPTS*CH/4
  float4 v = ((const float4*)out)[i];
  int c0 = (i * 4) & 63;
  float vals[4] = {v.x, v.y, v.z, v.w};
  float res[4];
  #pragma unroll
  for (int q = 0; q < 4; q++){
    int c = c0 + q;
    float mean = stats[c] * (1.0f/NPTS);
    float var  = stats[64+c] * (1.0f/NPTS) - mean*mean;
    float inv  = rsqrtf(var + 1e-5f);
    float y = (vals[q] - mean) * inv * g[c] + b[c];
    res[q] = fmaxf(y, 0.0f);
  }
  float4 r; r.x=res[0]; r.y=res[1]; r.z=res[2]; r.w=res[3];
  ((float4*)out)[i] = r;
}

extern "C" void kernel_launch(void* const* d_in, const int* in_sizes, int n_in,
                              void* d_out, int out_size, void* d_ws, size_t ws_size,
                              hipStream_t stream) {
  const float* feat   = (const float*)d_in[0];
  const int*   kmap   = (const int*)d_in[3];
  const float* weight = (const float*)d_in[4];
  const float* bnw    = (const float*)d_in[5];
  const float* bnb    = (const float*)d_in[6];
  float* out = (float*)d_out;

  char* ws = (char*)d_ws;
  size_t cur = 0;
  auto take = [&](size_t bytes){
    cur = (cur + 255) & ~(size_t)255;
    size_t p = cur; cur += bytes; return p;
  };
  float* stats          = (float*)(ws + take(2*CH*sizeof(float)));
  float* partials       = (float*)(ws + take((size_t)NBLK*128*sizeof(float)));
  int* cnt              = (int*)(ws + take((size_t)NSEG*4));
  int* loc              = (int*)(ws + take((size_t)NSEG*4));
  int* cursor           = (int*)(ws + take((size_t)NSEG*4));
  int* btot             = (int*)(ws + take(256*4));
  int* bbase            = (int*)(ws + take(256*4));
  unsigned short* wpack = (unsigned short*)(ws + take((size_t)KVOL*CH*CH*2));
  int* records          = (int*)(ws + take((size_t)TP*4));
  size_t featb_off      = take((size_t)NPTS*CH*2);
  bool useBf16 = (ws_size >= cur);
  unsigned short* featb = (unsigned short*)(ws + featb_off);

  hipMemsetAsync(cnt, 0, (size_t)NSEG*4, stream);

  k_pack_w<<<(KVOL*CH*CH + 255)/256, 256, 0, stream>>>(weight, wpack);
  if (useBf16)
    k_conv_feat<<<NPTS*CH/4/256, 256, 0, stream>>>(feat, featb);

  const int2* km = (const int2*)kmap;
  k_count<<<TP/256, 256, 0, stream>>>(km, cnt);
  k_scan1<<<256, 256, 0, stream>>>(cnt, loc, btot);
  k_scan2<<<1, 256, 0, stream>>>(btot, bbase);
  k_init<<<NSEG/256, 256, 0, stream>>>(loc, cursor, bbase);
  k_scatter<<<TP/256, 256, 0, stream>>>(km, cursor, records);

  if (useBf16)
    k_conv4<true><<<NBLK, 256, 0, stream>>>(featb, feat, wpack, records, loc, cnt, out, partials);
  else
    k_conv4<false><<<NBLK, 256, 0, stream>>>(featb, feat, wpack, records, loc, cnt, out, partials);

  k_statred<<<1, 128, 0, stream>>>(partials, stats);
  k_bn<<<NPTS*CH/4/256, 256, 0, stream>>>(out, stats, bnw, bnb);
}

// Round 5
// 361.601 us; speedup vs baseline: 2.3887x; 1.4032x over previous
//
#include <hip/hip_runtime.h>

#define NPTS 262144
#define KVOL 27
#define NPAIRS 65536
#define TP (KVOL*NPAIRS)     // 1769472 pairs
#define CH 64
#define NT32 (NPTS/32)       // 8192 32-row output tiles
#define NSEG (NT32*32)       // 262144 segments (k padded to 32)
#define NBLK2 2048           // conv blocks (4 waves, each owns a 32-row tile)
#define MAXR 12              // max collision rounds per (tile,k,slot) — P(exceed) < 1e-9

typedef __attribute__((ext_vector_type(8))) short bf16x8;
typedef __attribute__((ext_vector_type(4))) float f32x4;

__device__ inline unsigned short f2bf(float x){
  unsigned int u = __float_as_uint(x);
  u += 0x7FFFu + ((u >> 16) & 1u);   // RNE
  return (unsigned short)(u >> 16);
}

__device__ inline bf16x8 pack8(float4 a, float4 b){
  bf16x8 r;
  r[0]=(short)f2bf(a.x); r[1]=(short)f2bf(a.y); r[2]=(short)f2bf(a.z); r[3]=(short)f2bf(a.w);
  r[4]=(short)f2bf(b.x); r[5]=(short)f2bf(b.y); r[6]=(short)f2bf(b.z); r[7]=(short)f2bf(b.w);
  return r;
}

// ---- feat fp32 -> bf16 ----
__global__ void k_conv_feat(const float* __restrict__ f, unsigned short* __restrict__ o){
  int i = blockIdx.x * blockDim.x + threadIdx.x;   // NPTS*CH/4
  float4 v = ((const float4*)f)[i];
  ushort4 r;
  r.x = f2bf(v.x); r.y = f2bf(v.y); r.z = f2bf(v.z); r.w = f2bf(v.w);
  ((ushort4*)o)[i] = r;
}

// ---- weight fp32 [K][Cin][Cout] -> bf16 packed [k][kb][col][j] ----
__global__ void k_pack_w(const float* __restrict__ w, unsigned short* __restrict__ o){
  int i = blockIdx.x * blockDim.x + threadIdx.x;
  if (i >= KVOL*CH*CH) return;
  int j = i & 7, col = (i >> 3) & 63, kb = (i >> 9) & 7, k = i >> 12;
  o[i] = f2bf(w[(k*CH + kb*8 + j)*CH + col]);
}

// ---- histogram pairs into (tile32,k) segments ----
__global__ void k_count(const int2* __restrict__ km, int* __restrict__ cnt){
  int i = blockIdx.x*256 + threadIdx.x;   // TP
  int2 io = km[i];
  int k = i >> 16;
  atomicAdd(&cnt[((io.y >> 5) << 5) | k], 1);
}

// ---- hierarchical exclusive scan over NSEG counters ----
__global__ void k_scan1(const int* __restrict__ cnt, int* __restrict__ loc, int* __restrict__ btot){
  int blk = blockIdx.x, t = threadIdx.x;        // 128 blocks x 256 thr, 8 segs/thr
  int base = blk*2048 + t*8;
  int c[8]; int s = 0;
  #pragma unroll
  for (int i = 0; i < 8; i++){ c[i] = s; s += cnt[base+i]; }
  int l = t & 63;
  int v = s;
  #pragma unroll
  for (int d = 1; d < 64; d <<= 1){ int u = __shfl_up(v, d, 64); if (l >= d) v += u; }
  __shared__ int wt[4], wb[4];
  if (l == 63) wt[t>>6] = v;
  __syncthreads();
  if (t == 0){ int a = 0; for (int w = 0; w < 4; w++){ wb[w] = a; a += wt[w]; } }
  __syncthreads();
  int tb = wb[t>>6] + v - s;
  #pragma unroll
  for (int i = 0; i < 8; i++) loc[base+i] = tb + c[i];
  if (t == 255) btot[blk] = tb + s;
}

__global__ void k_scan2(const int* __restrict__ btot, int* __restrict__ bbase){
  __shared__ int sm_[128];
  int t = threadIdx.x;    // 128
  int mine = btot[t];
  sm_[t] = mine;
  __syncthreads();
  for (int d = 1; d < 128; d <<= 1){
    int v = (t >= d) ? sm_[t-d] : 0;
    __syncthreads();
    sm_[t] += v;
    __syncthreads();
  }
  bbase[t] = sm_[t] - mine;   // exclusive
}

// ---- finalize: segd = (begin, count), cursor = begin ----
__global__ void k_init(const int* __restrict__ loc, const int* __restrict__ cnt,
                       const int* __restrict__ bbase, int2* __restrict__ segd,
                       int* __restrict__ cursor){
  int i = blockIdx.x*256 + threadIdx.x;   // NSEG
  int a = loc[i] + bbase[i >> 11];
  segd[i] = make_int2(a, cnt[i]);
  cursor[i] = a;
}

// ---- scatter packed records (in:18b | slot:5b) ----
__global__ void k_scatter(const int2* __restrict__ km, int* __restrict__ cursor,
                          int* __restrict__ records){
  int i = blockIdx.x*256 + threadIdx.x;
  int2 io = km[i];
  int k = i >> 16;
  int pos = atomicAdd(&cursor[((io.y >> 5) << 5) | k], 1);
  records[pos] = io.x | ((io.y & 31) << 18);
}

// ---- conv: wave owns 32 output rows; acc in registers; LDS slot-table routing ----
template<bool BF16G>
__global__ __launch_bounds__(256, 4) void k_conv5(
    const unsigned short* __restrict__ featb, const float* __restrict__ featf,
    const unsigned short* __restrict__ wpack, const int* __restrict__ records,
    const int2* __restrict__ segd, float* __restrict__ out, float* __restrict__ partials)
{
  __shared__ int lcnt[4][32];
  __shared__ int lslot[4][MAXR*32];
  __shared__ float sred[4][2][64];

  int tid = threadIdx.x;
  int wv = tid>>6, l = tid&63, lg = l>>4, li = l&15;
  int t32 = blockIdx.x*4 + wv;      // 32-row tile
  int segbase = t32 << 5;

  const bf16x8* wp = (const bf16x8*)wpack;
  const bf16x8* fb = (const bf16x8*)featb;
  const float4* ff = (const float4*)featf;

  f32x4 acc[2][4];
  #pragma unroll
  for (int rt = 0; rt < 2; rt++)
    #pragma unroll
    for (int ct = 0; ct < 4; ct++) acc[rt][ct] = (f32x4)(0.0f);

  int2 sd = segd[segbase];
  for (int k = 0; k < KVOL; k++){
    int2 sd_next = segd[segbase + ((k < KVOL-1) ? k+1 : k)];  // prefetch
    int beg = sd.x, tot = sd.y;
    if (tot > 0){
      // B fragments for offset k
      bf16x8 B[4][2];
      #pragma unroll
      for (int ct = 0; ct < 4; ct++)
        #pragma unroll
        for (int h = 0; h < 2; h++)
          B[ct][h] = wp[(k*8 + h*4 + lg)*64 + ct*16 + li];

      for (int c0 = 0; c0 < tot; c0 += 64){
        int cc = min(64, tot - c0);
        if (l < 32) lcnt[wv][l] = 0;
        int rank = -1;
        int rec = 0;
        if (l < cc){
          rec = records[beg + c0 + l];
          int slot = (rec >> 18) & 31;
          rank = atomicAdd(&lcnt[wv][slot], 1);
          if (rank < MAXR) lslot[wv][rank*32 + slot] = rec;
        }
        int cnt0 = min(lcnt[wv][li], MAXR);
        int cnt1 = min(lcnt[wv][16 + li], MAXR);
        for (int r = 0; r < MAXR; r++){
          int rec0 = lslot[wv][r*32 + li];
          int rec1 = lslot[wv][r*32 + 16 + li];
          bool v0 = (r < cnt0), v1 = (r < cnt1);
          bf16x8 A00 = (bf16x8)(short)0, A01 = (bf16x8)(short)0;
          bf16x8 A10 = (bf16x8)(short)0, A11 = (bf16x8)(short)0;
          if (v0){
            int in0 = rec0 & 0x3FFFF;
            if (BF16G){ A00 = fb[in0*8 + lg]; A01 = fb[in0*8 + 4 + lg]; }
            else {
              float4 u0 = ff[in0*16 + lg*2],     u1 = ff[in0*16 + lg*2 + 1];
              float4 u2 = ff[in0*16 + 8 + lg*2], u3 = ff[in0*16 + 8 + lg*2 + 1];
              A00 = pack8(u0, u1); A01 = pack8(u2, u3);
            }
          }
          if (v1){
            int in1 = rec1 & 0x3FFFF;
            if (BF16G){ A10 = fb[in1*8 + lg]; A11 = fb[in1*8 + 4 + lg]; }
            else {
              float4 u0 = ff[in1*16 + lg*2],     u1 = ff[in1*16 + lg*2 + 1];
              float4 u2 = ff[in1*16 + 8 + lg*2], u3 = ff[in1*16 + 8 + lg*2 + 1];
              A10 = pack8(u0, u1); A11 = pack8(u2, u3);
            }
          }
          #pragma unroll
          for (int ct = 0; ct < 4; ct++){
            acc[0][ct] = __builtin_amdgcn_mfma_f32_16x16x32_bf16(A00, B[ct][0], acc[0][ct], 0, 0, 0);
            acc[0][ct] = __builtin_amdgcn_mfma_f32_16x16x32_bf16(A01, B[ct][1], acc[0][ct], 0, 0, 0);
            acc[1][ct] = __builtin_amdgcn_mfma_f32_16x16x32_bf16(A10, B[ct][0], acc[1][ct], 0, 0, 0);
            acc[1][ct] = __builtin_amdgcn_mfma_f32_16x16x32_bf16(A11, B[ct][1], acc[1][ct], 0, 0, 0);
          }
          if (__ballot(rank > r) == 0ull) break;
        }
      }
    }
    sd = sd_next;
  }

  // flush 32x64 rows from registers
  #pragma unroll
  for (int rt = 0; rt < 2; rt++)
    #pragma unroll
    for (int r = 0; r < 4; r++){
      int row = t32*32 + rt*16 + lg*4 + r;
      #pragma unroll
      for (int ct = 0; ct < 4; ct++)
        out[row*CH + ct*16 + li] = acc[rt][ct][r];
    }

  // BN stats partials
  float s1[4], s2[4];
  #pragma unroll
  for (int ct = 0; ct < 4; ct++){
    float a1 = 0.f, a2 = 0.f;
    #pragma unroll
    for (int rt = 0; rt < 2; rt++)
      #pragma unroll
      for (int r = 0; r < 4; r++){
        float v = acc[rt][ct][r];
        a1 += v; a2 += v*v;
      }
    a1 += __shfl_xor(a1, 16, 64); a1 += __shfl_xor(a1, 32, 64);
    a2 += __shfl_xor(a2, 16, 64); a2 += __shfl_xor(a2, 32, 64);
    s1[ct] = a1; s2[ct] = a2;
  }
  __syncthreads();   // lslot reuse barrier not needed; protects sred lifetime only
  if (l < 16){
    #pragma unroll
    for (int ct = 0; ct < 4; ct++){
      sred[wv][0][ct*16 + li] = s1[ct];
      sred[wv][1][ct*16 + li] = s2[ct];
    }
  }
  __syncthreads();
  if (tid < 128){
    int h = tid >> 6, c = tid & 63;
    float p = sred[0][h][c] + sred[1][h][c] + sred[2][h][c] + sred[3][h][c];
    partials[blockIdx.x*128 + tid] = p;
  }
}

// ---- parallel final stats reduce: one block per stat entry ----
__global__ void k_statred(const float* __restrict__ partials, float* __restrict__ stats){
  __shared__ float sm_[256];
  int c = blockIdx.x;       // 0..127
  int t = threadIdx.x;      // 256
  float s = 0.f;
  for (int b = t; b < NBLK2; b += 256) s += partials[b*128 + c];
  sm_[t] = s;
  __syncthreads();
  for (int d = 128; d > 0; d >>= 1){
    if (t < d) sm_[t] += sm_[t+d];
    __syncthreads();
  }
  if (t == 0) stats[c] = sm_[0];
}

// ---- BN (batch stats, biased var) + ReLU, in place ----
__global__ void k_bn(float* __restrict__ out, const float* __restrict__ stats,
                     const float* __restrict__ g, const float* __restrict__ b){
  int i = blockIdx.x * blockDim.x + threadIdx.x;  // NPTS*CH/4
  float4 v = ((const float4*)out)[i];
  int c0 = (i * 4) & 63;
  float vals[4] = {v.x, v.y, v.z, v.w};
  float res[4];
  #pragma unroll
  for (int q = 0; q < 4; q++){
    int c = c0 + q;
    float mean = stats[c] * (1.0f/NPTS);
    float var  = stats[64+c] * (1.0f/NPTS) - mean*mean;
    float inv  = rsqrtf(var + 1e-5f);
    float y = (vals[q] - mean) * inv * g[c] + b[c];
    res[q] = fmaxf(y, 0.0f);
  }
  float4 r; r.x=res[0]; r.y=res[1]; r.z=res[2]; r.w=res[3];
  ((float4*)out)[i] = r;
}

extern "C" void kernel_launch(void* const* d_in, const int* in_sizes, int n_in,
                              void* d_out, int out_size, void* d_ws, size_t ws_size,
                              hipStream_t stream) {
  const float* feat   = (const float*)d_in[0];
  const int*   kmap   = (const int*)d_in[3];
  const float* weight = (const float*)d_in[4];
  const float* bnw    = (const float*)d_in[5];
  const float* bnb    = (const float*)d_in[6];
  float* out = (float*)d_out;

  char* ws = (char*)d_ws;
  size_t cur = 0;
  auto take = [&](size_t bytes){
    cur = (cur + 255) & ~(size_t)255;
    size_t p = cur; cur += bytes; return p;
  };
  float* stats          = (float*)(ws + take(2*CH*sizeof(float)));
  float* partials       = (float*)(ws + take((size_t)NBLK2*128*sizeof(float)));
  int* cnt              = (int*)(ws + take((size_t)NSEG*4));
  int* loc              = (int*)(ws + take((size_t)NSEG*4));
  int* cursor           = (int*)(ws + take((size_t)NSEG*4));
  int2* segd            = (int2*)(ws + take((size_t)NSEG*8));
  int* btot             = (int*)(ws + take(128*4));
  int* bbase            = (int*)(ws + take(128*4));
  unsigned short* wpack = (unsigned short*)(ws + take((size_t)KVOL*CH*CH*2));
  int* records          = (int*)(ws + take((size_t)TP*4));
  size_t featb_off      = take((size_t)NPTS*CH*2);
  bool useBf16 = (ws_size >= cur);
  unsigned short* featb = (unsigned short*)(ws + featb_off);

  hipMemsetAsync(cnt, 0, (size_t)NSEG*4, stream);

  k_pack_w<<<(KVOL*CH*CH + 255)/256, 256, 0, stream>>>(weight, wpack);
  if (useBf16)
    k_conv_feat<<<NPTS*CH/4/256, 256, 0, stream>>>(feat, featb);

  const int2* km = (const int2*)kmap;
  k_count<<<TP/256, 256, 0, stream>>>(km, cnt);
  k_scan1<<<128, 256, 0, stream>>>(cnt, loc, btot);
  k_scan2<<<1, 128, 0, stream>>>(btot, bbase);
  k_init<<<NSEG/256, 256, 0, stream>>>(loc, cnt, bbase, segd, cursor);
  k_scatter<<<TP/256, 256, 0, stream>>>(km, cursor, records);

  if (useBf16)
    k_conv5<true><<<NBLK2, 256, 0, stream>>>(featb, feat, wpack, records, segd, out, partials);
  else
    k_conv5<false><<<NBLK2, 256, 0, stream>>>(featb, feat, wpack, records, segd, out, partials);

  k_statred<<<128, 256, 0, stream>>>(partials, stats);
  k_bn<<<NPTS*CH/4/256, 256, 0, stream>>>(out, stats, bnw, bnb);
}

// Round 6
// 262.477 us; speedup vs baseline: 3.2908x; 1.3776x over previous
//
#include <hip/hip_runtime.h>

#define NPTS 262144
#define KVOL 27
#define NPAIRS 65536
#define TP (KVOL*NPAIRS)     // 1769472 pairs
#define CH 64
#define NT32 (NPTS/32)       // 8192 32-row output tiles
#define NSEG (NT32*32)       // 262144 segments (k padded to 32)
#define NBLK2 2048           // conv blocks (4 waves, each owns a 32-row tile)
#define MAXR 12              // max collision rounds; P(exceed) < 1e-9

typedef __attribute__((ext_vector_type(8))) short bf16x8;
typedef __attribute__((ext_vector_type(4))) float f32x4;

__device__ inline unsigned short f2bf(float x){
  unsigned int u = __float_as_uint(x);
  u += 0x7FFFu + ((u >> 16) & 1u);   // RNE
  return (unsigned short)(u >> 16);
}

__device__ inline bf16x8 pack8(float4 a, float4 b){
  bf16x8 r;
  r[0]=(short)f2bf(a.x); r[1]=(short)f2bf(a.y); r[2]=(short)f2bf(a.z); r[3]=(short)f2bf(a.w);
  r[4]=(short)f2bf(b.x); r[5]=(short)f2bf(b.y); r[6]=(short)f2bf(b.z); r[7]=(short)f2bf(b.w);
  return r;
}

// ---- fused: feat->bf16 (bf16 path), weight pack, count + rank capture ----
template<bool BF16G>
__global__ void k_pre(const float* __restrict__ feat, const float* __restrict__ w,
                      const int2* __restrict__ km, unsigned short* __restrict__ featb,
                      unsigned short* __restrict__ wpack, int* __restrict__ cnt,
                      unsigned short* __restrict__ rankb){
  int i = blockIdx.x*256 + threadIdx.x;
  if (BF16G){
    float4 v = ((const float4*)feat)[i];     // grid sized to NPTS*CH/4
    ushort4 r;
    r.x = f2bf(v.x); r.y = f2bf(v.y); r.z = f2bf(v.z); r.w = f2bf(v.w);
    ((ushort4*)featb)[i] = r;
  }
  if (i < TP){
    int2 io = km[i];
    int k = i >> 16;
    int seg = ((io.y >> 5) << 5) | k;
    int rank = atomicAdd(&cnt[seg], 1);
    rankb[i] = (unsigned short)rank;
  }
  if (i < KVOL*CH*CH){
    int j = i & 7, col = (i >> 3) & 63, kb = (i >> 9) & 7, k = i >> 12;
    wpack[i] = f2bf(w[(k*CH + kb*8 + j)*CH + col]);
  }
}

// ---- hierarchical exclusive scan over NSEG counters ----
__global__ void k_scan1(const int* __restrict__ cnt, int* __restrict__ loc, int* __restrict__ btot){
  int blk = blockIdx.x, t = threadIdx.x;        // 128 blocks x 256 thr, 8 segs/thr
  int base = blk*2048 + t*8;
  int c[8]; int s = 0;
  #pragma unroll
  for (int i = 0; i < 8; i++){ c[i] = s; s += cnt[base+i]; }
  int l = t & 63;
  int v = s;
  #pragma unroll
  for (int d = 1; d < 64; d <<= 1){ int u = __shfl_up(v, d, 64); if (l >= d) v += u; }
  __shared__ int wt[4], wb[4];
  if (l == 63) wt[t>>6] = v;
  __syncthreads();
  if (t == 0){ int a = 0; for (int w = 0; w < 4; w++){ wb[w] = a; a += wt[w]; } }
  __syncthreads();
  int tb = wb[t>>6] + v - s;
  #pragma unroll
  for (int i = 0; i < 8; i++) loc[base+i] = tb + c[i];
  if (t == 255) btot[blk] = tb + s;
}

__global__ void k_scan2(const int* __restrict__ btot, int* __restrict__ bbase){
  __shared__ int sm_[128];
  int t = threadIdx.x;    // 128
  int mine = btot[t];
  sm_[t] = mine;
  __syncthreads();
  for (int d = 1; d < 128; d <<= 1){
    int v = (t >= d) ? sm_[t-d] : 0;
    __syncthreads();
    sm_[t] += v;
    __syncthreads();
  }
  bbase[t] = sm_[t] - mine;   // exclusive
}

// ---- finalize: segd = (global begin, count) ----
__global__ void k_init(const int* __restrict__ loc, const int* __restrict__ cnt,
                       const int* __restrict__ bbase, int2* __restrict__ segd){
  int i = blockIdx.x*256 + threadIdx.x;   // NSEG
  segd[i] = make_int2(loc[i] + bbase[i >> 11], cnt[i]);
}

// ---- scatter packed records (in:18b | slot:5b) via stored rank, no atomics ----
__global__ void k_scatter(const int2* __restrict__ km, const unsigned short* __restrict__ rankb,
                          const int2* __restrict__ segd, int* __restrict__ records){
  int i = blockIdx.x*256 + threadIdx.x;
  int2 io = km[i];
  int k = i >> 16;
  int seg = ((io.y >> 5) << 5) | k;
  int pos = segd[seg].x + rankb[i];
  records[pos] = io.x | ((io.y & 31) << 18);
}

// ---- conv: wave owns 32 rows; reg acc; LDS slot table; rec prefetch; half-skip ----
template<bool BF16G>
__global__ __launch_bounds__(256, 4) void k_conv6(
    const unsigned short* __restrict__ featb, const float* __restrict__ featf,
    const unsigned short* __restrict__ wpack, const int* __restrict__ records,
    const int2* __restrict__ segd, float* __restrict__ out, float* __restrict__ partials)
{
  __shared__ int lcnt[4][32];
  __shared__ int lslot[4][MAXR*32];
  __shared__ float sred[4][2][64];

  int tid = threadIdx.x;
  int wv = tid>>6, l = tid&63, lg = l>>4, li = l&15;
  int t32 = blockIdx.x*4 + wv;      // 32-row tile
  int segbase = t32 << 5;

  const bf16x8* fb = (const bf16x8*)featb;
  const float4* ff = (const float4*)featf;
  // per-lane B base: vec index (h*4+lg)*64 + ct*16 + li; k advances by 512 vecs
  const bf16x8* wbase = ((const bf16x8*)wpack) + lg*64 + li;

  f32x4 acc[2][4];
  #pragma unroll
  for (int rt = 0; rt < 2; rt++)
    #pragma unroll
    for (int ct = 0; ct < 4; ct++) acc[rt][ct] = (f32x4)(0.0f);

  int2 sd  = segd[segbase];
  int2 sd1 = segd[segbase + 1];
  int rec_pf = 0;
  if (l < sd.y) rec_pf = records[sd.x + l];

  for (int k = 0; k < KVOL; k++){
    int2 sd2 = segd[segbase + min(k + 2, 31)];
    int rec_nx = 0;
    if (l < sd1.y) rec_nx = records[sd1.x + l];   // prefetch next k's first chunk

    int beg = sd.x, tot = sd.y;
    if (tot > 0){
      // B fragments for offset k
      bf16x8 B[4][2];
      #pragma unroll
      for (int ct = 0; ct < 4; ct++)
        #pragma unroll
        for (int h = 0; h < 2; h++)
          B[ct][h] = wbase[k*512 + h*256 + ct*16];

      int rec = rec_pf;
      for (int c0 = 0; c0 < tot; c0 += 64){
        int cc = min(64, tot - c0);
        if (c0 > 0 && l < cc) rec = records[beg + c0 + l];  // rare slow path
        if (l < 32) lcnt[wv][l] = 0;
        int rank = -1;
        if (l < cc){
          int slot = (rec >> 18) & 31;
          rank = atomicAdd(&lcnt[wv][slot], 1);
          if (rank < MAXR) lslot[wv][rank*32 + slot] = rec;
        }
        int cnt0 = min(lcnt[wv][li], MAXR);
        int cnt1 = min(lcnt[wv][16 + li], MAXR);
        for (int r = 0; r < MAXR; r++){
          int rec0 = lslot[wv][r*32 + li];
          int rec1 = lslot[wv][r*32 + 16 + li];
          bool v0 = (r < cnt0), v1 = (r < cnt1);
          unsigned long long b0 = __ballot(v0), b1 = __ballot(v1);
          bf16x8 A00 = (bf16x8)(short)0, A01 = (bf16x8)(short)0;
          bf16x8 A10 = (bf16x8)(short)0, A11 = (bf16x8)(short)0;
          if (v0){
            int in0 = rec0 & 0x3FFFF;
            if (BF16G){ A00 = fb[in0*8 + lg]; A01 = fb[in0*8 + 4 + lg]; }
            else {
              float4 u0 = ff[in0*16 + lg*2],     u1 = ff[in0*16 + lg*2 + 1];
              float4 u2 = ff[in0*16 + 8 + lg*2], u3 = ff[in0*16 + 8 + lg*2 + 1];
              A00 = pack8(u0, u1); A01 = pack8(u2, u3);
            }
          }
          if (v1){
            int in1 = rec1 & 0x3FFFF;
            if (BF16G){ A10 = fb[in1*8 + lg]; A11 = fb[in1*8 + 4 + lg]; }
            else {
              float4 u0 = ff[in1*16 + lg*2],     u1 = ff[in1*16 + lg*2 + 1];
              float4 u2 = ff[in1*16 + 8 + lg*2], u3 = ff[in1*16 + 8 + lg*2 + 1];
              A10 = pack8(u0, u1); A11 = pack8(u2, u3);
            }
          }
          if (b0){
            #pragma unroll
            for (int ct = 0; ct < 4; ct++){
              acc[0][ct] = __builtin_amdgcn_mfma_f32_16x16x32_bf16(A00, B[ct][0], acc[0][ct], 0, 0, 0);
              acc[0][ct] = __builtin_amdgcn_mfma_f32_16x16x32_bf16(A01, B[ct][1], acc[0][ct], 0, 0, 0);
            }
          }
          if (b1){
            #pragma unroll
            for (int ct = 0; ct < 4; ct++){
              acc[1][ct] = __builtin_amdgcn_mfma_f32_16x16x32_bf16(A10, B[ct][0], acc[1][ct], 0, 0, 0);
              acc[1][ct] = __builtin_amdgcn_mfma_f32_16x16x32_bf16(A11, B[ct][1], acc[1][ct], 0, 0, 0);
            }
          }
          if (__ballot(rank > r) == 0ull) break;
        }
      }
    }
    rec_pf = rec_nx; sd = sd1; sd1 = sd2;
  }

  // flush 32x64 rows from registers
  #pragma unroll
  for (int rt = 0; rt < 2; rt++)
    #pragma unroll
    for (int r = 0; r < 4; r++){
      int row = t32*32 + rt*16 + lg*4 + r;
      #pragma unroll
      for (int ct = 0; ct < 4; ct++)
        out[row*CH + ct*16 + li] = acc[rt][ct][r];
    }

  // BN stats partials
  float s1[4], s2[4];
  #pragma unroll
  for (int ct = 0; ct < 4; ct++){
    float a1 = 0.f, a2 = 0.f;
    #pragma unroll
    for (int rt = 0; rt < 2; rt++)
      #pragma unroll
      for (int r = 0; r < 4; r++){
        float v = acc[rt][ct][r];
        a1 += v; a2 += v*v;
      }
    a1 += __shfl_xor(a1, 16, 64); a1 += __shfl_xor(a1, 32, 64);
    a2 += __shfl_xor(a2, 16, 64); a2 += __shfl_xor(a2, 32, 64);
    s1[ct] = a1; s2[ct] = a2;
  }
  __syncthreads();
  if (l < 16){
    #pragma unroll
    for (int ct = 0; ct < 4; ct++){
      sred[wv][0][ct*16 + li] = s1[ct];
      sred[wv][1][ct*16 + li] = s2[ct];
    }
  }
  __syncthreads();
  if (tid < 128){
    int h = tid >> 6, c = tid & 63;
    float p = sred[0][h][c] + sred[1][h][c] + sred[2][h][c] + sred[3][h][c];
    partials[blockIdx.x*128 + tid] = p;
  }
}

// ---- parallel final stats reduce ----
__global__ void k_statred(const float* __restrict__ partials, float* __restrict__ stats){
  __shared__ float sm_[256];
  int c = blockIdx.x;       // 0..127
  int t = threadIdx.x;      // 256
  float s = 0.f;
  for (int b = t; b < NBLK2; b += 256) s += partials[b*128 + c];
  sm_[t] = s;
  __syncthreads();
  for (int d = 128; d > 0; d >>= 1){
    if (t < d) sm_[t] += sm_[t+d];
    __syncthreads();
  }
  if (t == 0) stats[c] = sm_[0];
}

// ---- BN (batch stats, biased var) + ReLU, in place ----
__global__ void k_bn(float* __restrict__ out, const float* __restrict__ stats,
                     const float* __restrict__ g, const float* __restrict__ b){
  int i = blockIdx.x * blockDim.x + threadIdx.x;  // NPTS*CH/4
  float4 v = ((const float4*)out)[i];
  int c0 = (i * 4) & 63;
  float vals[4] = {v.x, v.y, v.z, v.w};
  float res[4];
  #pragma unroll
  for (int q = 0; q < 4; q++){
    int c = c0 + q;
    float mean = stats[c] * (1.0f/NPTS);
    float var  = stats[64+c] * (1.0f/NPTS) - mean*mean;
    float inv  = rsqrtf(var + 1e-5f);
    float y = (vals[q] - mean) * inv * g[c] + b[c];
    res[q] = fmaxf(y, 0.0f);
  }
  float4 r; r.x=res[0]; r.y=res[1]; r.z=res[2]; r.w=res[3];
  ((float4*)out)[i] = r;
}

extern "C" void kernel_launch(void* const* d_in, const int* in_sizes, int n_in,
                              void* d_out, int out_size, void* d_ws, size_t ws_size,
                              hipStream_t stream) {
  const float* feat   = (const float*)d_in[0];
  const int*   kmap   = (const int*)d_in[3];
  const float* weight = (const float*)d_in[4];
  const float* bnw    = (const float*)d_in[5];
  const float* bnb    = (const float*)d_in[6];
  float* out = (float*)d_out;

  char* ws = (char*)d_ws;
  size_t cur = 0;
  auto take = [&](size_t bytes){
    cur = (cur + 255) & ~(size_t)255;
    size_t p = cur; cur += bytes; return p;
  };
  float* stats          = (float*)(ws + take(2*CH*sizeof(float)));
  float* partials       = (float*)(ws + take((size_t)NBLK2*128*sizeof(float)));
  int* cnt              = (int*)(ws + take((size_t)NSEG*4));
  int* loc              = (int*)(ws + take((size_t)NSEG*4));
  int2* segd            = (int2*)(ws + take((size_t)NSEG*8));
  int* btot             = (int*)(ws + take(128*4));
  int* bbase            = (int*)(ws + take(128*4));
  unsigned short* wpack = (unsigned short*)(ws + take((size_t)KVOL*CH*CH*2));
  unsigned short* rankb = (unsigned short*)(ws + take((size_t)TP*2));
  int* records          = (int*)(ws + take((size_t)TP*4));
  size_t featb_off      = take((size_t)NPTS*CH*2);
  bool useBf16 = (ws_size >= cur);
  unsigned short* featb = (unsigned short*)(ws + featb_off);

  hipMemsetAsync(cnt, 0, (size_t)NSEG*4, stream);

  const int2* km = (const int2*)kmap;
  if (useBf16)
    k_pre<true><<<NPTS*CH/4/256, 256, 0, stream>>>(feat, weight, km, featb, wpack, cnt, rankb);
  else
    k_pre<false><<<TP/256, 256, 0, stream>>>(feat, weight, km, featb, wpack, cnt, rankb);

  k_scan1<<<128, 256, 0, stream>>>(cnt, loc, btot);
  k_scan2<<<1, 128, 0, stream>>>(btot, bbase);
  k_init<<<NSEG/256, 256, 0, stream>>>(loc, cnt, bbase, segd);
  k_scatter<<<TP/256, 256, 0, stream>>>(km, rankb, segd, records);

  if (useBf16)
    k_conv6<true><<<NBLK2, 256, 0, stream>>>(featb, feat, wpack, records, segd, out, partials);
  else
    k_conv6<false><<<NBLK2, 256, 0, stream>>>(featb, feat, wpack, records, segd, out, partials);

  k_statred<<<128, 256, 0, stream>>>(partials, stats);
  k_bn<<<NPTS*CH/4/256, 256, 0, stream>>>(out, stats, bnw, bnb);
}